// Round 14
// baseline (32.394 us; speedup 1.0000x reference)
//
#include <hip/hip_runtime.h>
#include <math.h>

#define LDIM 64
#define QT2 32   // queries per tile
#define QW 8     // queries per wave
#define LOG2E 1.4426950408889634f

static __device__ __forceinline__ float fast_exp2(float x) {
#if __has_builtin(__builtin_amdgcn_exp2f)
    return __builtin_amdgcn_exp2f(x);
#else
    return exp2f(x);
#endif
}

static __device__ __forceinline__ float4 ld4(const float* p) {
    return *(const float4*)p;
}

// K1: precompute + zero accumulators (R7 structure, V deleted).
//   Bi[c][g][o] = float4{ B[4g+j][o] },  B[l][o] = b1[l] + pos_obs[o]·(W1[3:6,l]-W1[6:9,l])
//   A[q][l]     = pos_query[q]·(W1[0:3,l]+W1[6:9,l])
//   P4[o]       = (x,y,z, mask ? batch+1 : 0)
//   w2s[l]      = W2[l]*log2e ;  acc/den zeroed
__global__ __launch_bounds__(256) void gano_pre(
    const float* __restrict__ pos_obs, const float* __restrict__ pos_query,
    const float* __restrict__ W1, const float* __restrict__ b1,
    const float* __restrict__ W2,
    const int* __restrict__ obs_mask, const int* __restrict__ obs_batch,
    float4* __restrict__ Bi, float4* __restrict__ P4,
    float* __restrict__ A, float* __restrict__ w2s, float* __restrict__ zeroR,
    int No, int NoA, int Nq, int zn)
{
    const int gid = blockIdx.x * blockDim.x + threadIdx.x;

    // Bi[c][g][o]
    if (gid < NoA * 16) {
        const int o = gid & 63, g = (gid >> 6) & 15, c = gid >> 10;
        const int oo = (c << 6) + o;
        float4 r = make_float4(0.f, 0.f, 0.f, 0.f);
        if (oo < No) {
            const float px = pos_obs[oo*3+0], py = pos_obs[oo*3+1], pz = pos_obs[oo*3+2];
            float* rr = (float*)&r;
            #pragma unroll
            for (int j = 0; j < 4; ++j) {
                const int l = 4 * g + j;
                float bb = b1[l];
                bb = fmaf(px, W1[3*LDIM+l] - W1[6*LDIM+l], bb);
                bb = fmaf(py, W1[4*LDIM+l] - W1[7*LDIM+l], bb);
                bb = fmaf(pz, W1[5*LDIM+l] - W1[8*LDIM+l], bb);
                rr[j] = bb;
            }
        }
        Bi[gid] = r;
    }
    // A[q][l]
    if (gid < Nq * LDIM) {
        const int q = gid >> 6, l = gid & 63;
        float a = pos_query[q*3+0] * (W1[0*LDIM+l] + W1[6*LDIM+l]);
        a = fmaf(pos_query[q*3+1], W1[1*LDIM+l] + W1[7*LDIM+l], a);
        a = fmaf(pos_query[q*3+2], W1[2*LDIM+l] + W1[8*LDIM+l], a);
        A[gid] = a;
    }
    if (gid < LDIM) w2s[gid] = W2[gid] * LOG2E;
    // P4[o]
    if (gid < NoA) {
        float4 pp = make_float4(0.f, 0.f, 0.f, 0.f);
        if (gid < No)
            pp = make_float4(pos_obs[gid*3+0], pos_obs[gid*3+1], pos_obs[gid*3+2],
                             obs_mask[gid] ? (float)(obs_batch[gid] + 1) : 0.0f);
        P4[gid] = pp;
    }
    // zero acc (Nq*64) + den (Nq), contiguous
    if (gid < zn) zeroR[gid] = 0.0f;
}

// K2: R7's verified 29.0us hot kernel, with ONE change: PV reads h_obs
// directly (same [No][64] layout V had) -- Wv applied in K3 (linearity,
// R9-validated). Fused logits + no-max e + PV-accumulate per (chunk, tile).
// Plain fire-and-forget atomicAdd (R8 lesson: no fences).
__global__ __launch_bounds__(256) void gano_accum(
    const float4* __restrict__ Bi, const float4* __restrict__ P4,
    const float* __restrict__ h_obs, const float* __restrict__ A,
    const float* __restrict__ w2s, const float* __restrict__ pos_query,
    const int* __restrict__ obs_batch, const int* __restrict__ query_batch,
    float* __restrict__ acc, float* __restrict__ den,
    int No, int Nq)
{
    const int c  = blockIdx.x;
    const int q0 = blockIdx.y * QT2;
    if ((c << 6) >= No) return;
    // batch-span intersection early-exit (both arrays sorted)
    const int c_lo = obs_batch[c << 6];
    const int c_hi = obs_batch[min((c << 6) + 63, No - 1)];
    if (c_lo > query_batch[min(q0 + QT2 - 1, Nq - 1)] || c_hi < query_batch[q0]) return;

    __shared__ float4 a4[QT2][16];      // [q][g] query-side preact
    __shared__ float4 w2_4[16];
    __shared__ float4 qp4[QT2];
    __shared__ float  e_lds[QT2][LDIM]; // [q][o], wave-private rows

    const int tid = threadIdx.x;
    for (int i = tid; i < QT2 * 16; i += 256)
        a4[i >> 4][i & 15] = ((const float4*)A)[((size_t)(q0 + (i >> 4)) << 4) + (i & 15)];
    if (tid < 16) w2_4[tid] = ((const float4*)w2s)[tid];
    if (tid < QT2) {
        const int q = min(q0 + tid, Nq - 1);
        qp4[tid] = make_float4(pos_query[q*3+0], pos_query[q*3+1], pos_query[q*3+2],
                               (float)(query_batch[q] + 1));
    }
    __syncthreads();

    const int lane = tid & 63, wid = tid >> 6;
    const float4 p = P4[(c << 6) + lane];
    const float4* Bc = Bi + ((size_t)c << 10) + lane;

    // ---- logits: lane = obs, 8 queries ----
    float lgq[QW];
    #pragma unroll
    for (int j = 0; j < QW; ++j) lgq[j] = 0.0f;
    #pragma unroll
    for (int g = 0; g < 16; ++g) {
        const float4 Bv = Bc[g << 6];
        const float4 w  = w2_4[g];
        #pragma unroll
        for (int j = 0; j < QW; ++j) {
            const float4 a = a4[wid * QW + j][g];
            lgq[j] = fmaf(fmaxf(a.x + Bv.x, 0.f), w.x, lgq[j]);
            lgq[j] = fmaf(fmaxf(a.y + Bv.y, 0.f), w.y, lgq[j]);
            lgq[j] = fmaf(fmaxf(a.z + Bv.z, 0.f), w.z, lgq[j]);
            lgq[j] = fmaf(fmaxf(a.w + Bv.w, 0.f), w.w, lgq[j]);
        }
    }

    // ---- mask + direct exp2; stash e into wave-private LDS rows ----
    float ds[QW];
    #pragma unroll
    for (int j = 0; j < QW; ++j) {
        const float4 qp = qp4[wid * QW + j];
        const float dx = qp.x - p.x, dy = qp.y - p.y, dz = qp.z - p.z;
        const float d2 = fmaf(dz, dz, fmaf(dy, dy, dx * dx));
        const bool valid = (p.w == qp.w) & (d2 <= 1.0f);
        const float e = valid ? fast_exp2(lgq[j]) : 0.0f;
        e_lds[wid * QW + j][lane] = e;
        ds[j] = e;
    }
    // denom: 8 interleaved shfl-reduce chains, one atomic per query
    #pragma unroll
    for (int msk = 32; msk; msk >>= 1) {
        #pragma unroll
        for (int j = 0; j < QW; ++j) ds[j] += __shfl_xor(ds[j], msk, 64);
    }
    if (lane == 0) {
        #pragma unroll
        for (int j = 0; j < QW; ++j) atomicAdd(&den[q0 + wid * QW + j], ds[j]);
    }

    // ---- PV: lane = hidden-input dim k; e via b128 broadcast ----
    const float* Hc = h_obs + ((size_t)c << 12) + lane;
    float pacc[QW];
    #pragma unroll
    for (int j = 0; j < QW; ++j) pacc[j] = 0.0f;
    if ((c << 6) + 64 <= No) {
        for (int oo = 0; oo < LDIM; oo += 4) {
            const float v0 = Hc[(oo + 0) << 6];
            const float v1 = Hc[(oo + 1) << 6];
            const float v2 = Hc[(oo + 2) << 6];
            const float v3 = Hc[(oo + 3) << 6];
            #pragma unroll
            for (int j = 0; j < QW; ++j) {
                const float4 e = *(const float4*)&e_lds[wid * QW + j][oo]; // broadcast
                pacc[j] = fmaf(e.x, v0, pacc[j]);
                pacc[j] = fmaf(e.y, v1, pacc[j]);
                pacc[j] = fmaf(e.z, v2, pacc[j]);
                pacc[j] = fmaf(e.w, v3, pacc[j]);
            }
        }
    } else {  // tail chunk: clamp rows (e is 0 there)
        for (int oo = 0; oo < LDIM; ++oo) {
            const int orow = min((c << 6) + oo, No - 1);
            const float v = h_obs[((size_t)orow << 6) + lane];
            #pragma unroll
            for (int j = 0; j < QW; ++j)
                pacc[j] = fmaf(e_lds[wid * QW + j][oo], v, pacc[j]);
        }
    }
    #pragma unroll
    for (int j = 0; j < QW; ++j)
        atomicAdd(&acc[(size_t)(q0 + wid * QW + j) * LDIM + lane], pacc[j]);
}

// K3: normalize + Wv epilogue + bv.  out[q] = (acc[q]/D) @ Wv + bv, or 0 if D==0.
__global__ __launch_bounds__(256) void gano_norm(
    const float* __restrict__ acc, const float* __restrict__ den,
    const float* __restrict__ Wv, const float* __restrict__ bv,
    float* __restrict__ out, int Nq)
{
    const int tid = threadIdx.x, lane = tid & 63, wid = tid >> 6;
    const int q0 = blockIdx.x * 8 + wid * 2;
    if (q0 >= Nq) return;

    __shared__ float r_lds[4][2][LDIM];

    const float D0 = den[q0];
    const float D1 = (q0 + 1 < Nq) ? den[q0 + 1] : 0.0f;
    const float rd0 = (D0 > 0.0f) ? 1.0f / D0 : 0.0f;
    const float rd1 = (D1 > 0.0f) ? 1.0f / D1 : 0.0f;
    r_lds[wid][0][lane] = acc[(size_t)q0 * LDIM + lane] * rd0;
    r_lds[wid][1][lane] = (q0 + 1 < Nq) ? acc[(size_t)(q0 + 1) * LDIM + lane] * rd1 : 0.0f;
    // wave-private: no barrier needed
    float o0 = 0.f, o1 = 0.f;
    #pragma unroll 8
    for (int k = 0; k < LDIM; ++k) {
        const float w = Wv[(k << 6) + lane];
        o0 = fmaf(r_lds[wid][0][k], w, o0);
        o1 = fmaf(r_lds[wid][1][k], w, o1);
    }
    const float b = bv[lane];
    out[(size_t)q0 * LDIM + lane] = (D0 > 0.0f) ? o0 + b : 0.0f;
    if (q0 + 1 < Nq)
        out[(size_t)(q0 + 1) * LDIM + lane] = (D1 > 0.0f) ? o1 + b : 0.0f;
}

extern "C" void kernel_launch(void* const* d_in, const int* in_sizes, int n_in,
                              void* d_out, int out_size, void* d_ws, size_t ws_size,
                              hipStream_t stream) {
    const float* h_obs     = (const float*)d_in[0];
    const float* pos_obs   = (const float*)d_in[1];
    const float* pos_query = (const float*)d_in[2];
    const float* W1        = (const float*)d_in[3];
    const float* b1        = (const float*)d_in[4];
    const float* W2        = (const float*)d_in[5];
    // d_in[6] = b2: constant shift, cancels in softmax -> unused
    const float* Wv        = (const float*)d_in[7];
    const float* bv        = (const float*)d_in[8];
    const int* obs_mask    = (const int*)d_in[9];
    const int* obs_batch   = (const int*)d_in[10];
    const int* query_batch = (const int*)d_in[11];

    const int No     = in_sizes[1] / 3;
    const int Nq     = in_sizes[2] / 3;
    const int NoA    = (No + 63) & ~63;
    const int nC     = NoA / 64;
    const int nTiles = (Nq + QT2 - 1) / QT2;
    const int zn     = Nq * (LDIM + 1);

    // ws layout (~0.9 MB): Bi | P4 | A | w2s | acc | den
    float4* Bi  = (float4*)d_ws;                   // NoA*16 float4
    float4* P4  = Bi + (size_t)NoA * 16;           // NoA float4
    float*  A   = (float*)(P4 + NoA);              // Nq*64 f
    float*  w2s = A + (size_t)Nq * LDIM;           // 64 f
    float*  acc = w2s + LDIM;                      // Nq*64 f (zeroed)
    float*  den = acc + (size_t)Nq * LDIM;         // Nq f    (zeroed)

    int gridN = NoA * 16;
    if (Nq * LDIM > gridN) gridN = Nq * LDIM;
    if (zn > gridN) gridN = zn;

    gano_pre<<<(gridN + 255) / 256, 256, 0, stream>>>(
        pos_obs, pos_query, W1, b1, W2, obs_mask, obs_batch,
        Bi, P4, A, w2s, acc, No, NoA, Nq, zn);

    dim3 g2(nC, nTiles);
    gano_accum<<<g2, 256, 0, stream>>>(Bi, P4, h_obs, A, w2s, pos_query,
                                       obs_batch, query_batch, acc, den, No, Nq);

    gano_norm<<<(Nq + 7) / 8, 256, 0, stream>>>(acc, den, Wv, bv, (float*)d_out, Nq);
}

// Round 15
// 28.892 us; speedup vs baseline: 1.1212x; 1.1212x over previous
//
#include <hip/hip_runtime.h>
#include <math.h>

#define LDIM 64
#define QT2 32   // queries per tile (block)
#define QW 8     // queries per wave
#define LOG2E 1.4426950408889634f

static __device__ __forceinline__ float fast_exp2(float x) {
#if __has_builtin(__builtin_amdgcn_exp2f)
    return __builtin_amdgcn_exp2f(x);
#else
    return exp2f(x);
#endif
}

// K1: precompute + zero accumulators.  (R7 verbatim -- empirical best 29.0us)
//   Bi[c][g][o] = float4{ B[4g+j][o] },  B[l][o] = b1[l] + pos_obs[o]·(W1[3:6,l]-W1[6:9,l])
//   V[o][l]     = bv[l] + h_obs[o]·Wv[:,l]
//   A[q][l]     = pos_query[q]·(W1[0:3,l]+W1[6:9,l])
//   P4[o]       = (x,y,z, mask ? batch+1 : 0)
//   w2s[l]      = W2[l]*log2e ;  acc/den zeroed
__global__ __launch_bounds__(256) void gano_pre(
    const float* __restrict__ h_obs, const float* __restrict__ pos_obs,
    const float* __restrict__ pos_query,
    const float* __restrict__ W1, const float* __restrict__ b1,
    const float* __restrict__ W2,
    const float* __restrict__ Wv, const float* __restrict__ bv,
    const int* __restrict__ obs_mask, const int* __restrict__ obs_batch,
    float4* __restrict__ Bi, float4* __restrict__ P4, float* __restrict__ V,
    float* __restrict__ A, float* __restrict__ w2s, float* __restrict__ zeroRegion,
    int No, int NoA, int Nq)
{
    const int gid = blockIdx.x * blockDim.x + threadIdx.x;
    if (gid >= NoA * LDIM) return;
    // V[o][l]
    {
        const int o = gid >> 6, l = gid & 63;
        float vv = 0.0f;
        if (o < No) {
            vv = bv[l];
            #pragma unroll 16
            for (int k = 0; k < LDIM; ++k)
                vv = fmaf(h_obs[o * LDIM + k], Wv[k * LDIM + l], vv);
        }
        V[gid] = vv;
    }
    // Bi[c][g][o]
    if (gid < NoA * 16) {
        const int o = gid & 63, g = (gid >> 6) & 15, c = gid >> 10;
        const int oo = (c << 6) + o;
        float4 r = make_float4(0.f, 0.f, 0.f, 0.f);
        if (oo < No) {
            const float px = pos_obs[oo*3+0], py = pos_obs[oo*3+1], pz = pos_obs[oo*3+2];
            float* rr = (float*)&r;
            #pragma unroll
            for (int j = 0; j < 4; ++j) {
                const int l = 4 * g + j;
                float bb = b1[l];
                bb = fmaf(px, W1[3*LDIM+l] - W1[6*LDIM+l], bb);
                bb = fmaf(py, W1[4*LDIM+l] - W1[7*LDIM+l], bb);
                bb = fmaf(pz, W1[5*LDIM+l] - W1[8*LDIM+l], bb);
                rr[j] = bb;
            }
        }
        Bi[gid] = r;
    }
    // A[q][l]
    if (gid < Nq * LDIM) {
        const int q = gid >> 6, l = gid & 63;
        float a = pos_query[q*3+0] * (W1[0*LDIM+l] + W1[6*LDIM+l]);
        a = fmaf(pos_query[q*3+1], W1[1*LDIM+l] + W1[7*LDIM+l], a);
        a = fmaf(pos_query[q*3+2], W1[2*LDIM+l] + W1[8*LDIM+l], a);
        A[gid] = a;
    }
    if (gid < LDIM) w2s[gid] = W2[gid] * LOG2E;
    // P4[o]
    if (gid < NoA) {
        float4 pp = make_float4(0.f, 0.f, 0.f, 0.f);
        if (gid < No)
            pp = make_float4(pos_obs[gid*3+0], pos_obs[gid*3+1], pos_obs[gid*3+2],
                             obs_mask[gid] ? (float)(obs_batch[gid] + 1) : 0.0f);
        P4[gid] = pp;
    }
    // zero acc (Nq*64) + den (Nq), contiguous
    if (gid < Nq * (LDIM + 1)) zeroRegion[gid] = 0.0f;
}

// K2: fused logits + e + PV-accumulate for one (64-obs chunk, 32-query tile).
// Wave = 8 queries x 64 obs (lane = obs). No-max softmax: e = 2^lg directly
// (logits structurally small; validated R6-R14, absmax 6e-5). Each wave
// transposes its own e through wave-private LDS (no barrier) and accumulates
// 8 query partials over the chunk, then plain atomicAdds to acc/den.
__global__ __launch_bounds__(256) void gano_accum(
    const float4* __restrict__ Bi, const float4* __restrict__ P4,
    const float* __restrict__ V, const float* __restrict__ A,
    const float* __restrict__ w2s, const float* __restrict__ pos_query,
    const int* __restrict__ obs_batch, const int* __restrict__ query_batch,
    float* __restrict__ acc, float* __restrict__ den,
    int No, int Nq)
{
    const int c  = blockIdx.x;
    const int q0 = blockIdx.y * QT2;
    if ((c << 6) >= No) return;
    // batch-span intersection early-exit (both arrays sorted)
    const int c_lo = obs_batch[c << 6];
    const int c_hi = obs_batch[min((c << 6) + 63, No - 1)];
    if (c_lo > query_batch[q0 + QT2 - 1] || c_hi < query_batch[q0]) return;

    __shared__ float4 a4[QT2][16];      // [q][g] query-side preact
    __shared__ float4 w2_4[16];
    __shared__ float4 qp4[QT2];
    __shared__ float  e_lds[QT2][LDIM]; // [q][o], wave-private rows

    const int tid = threadIdx.x;
    for (int i = tid; i < QT2 * 16; i += 256)
        a4[i >> 4][i & 15] = ((const float4*)A)[((size_t)(q0 + (i >> 4)) << 4) + (i & 15)];
    if (tid < 16) w2_4[tid] = ((const float4*)w2s)[tid];
    if (tid < QT2) {
        const int q = q0 + tid;
        qp4[tid] = make_float4(pos_query[q*3+0], pos_query[q*3+1], pos_query[q*3+2],
                               (float)(query_batch[q] + 1));
    }
    __syncthreads();

    const int lane = tid & 63, wid = tid >> 6;
    const float4 p = P4[(c << 6) + lane];
    const float4* Bc = Bi + ((size_t)c << 10) + lane;

    // ---- logits: lane = obs, 8 queries ----
    float lgq[QW];
    #pragma unroll
    for (int j = 0; j < QW; ++j) lgq[j] = 0.0f;
    #pragma unroll
    for (int g = 0; g < 16; ++g) {
        const float4 Bv = Bc[g << 6];
        const float4 w  = w2_4[g];
        #pragma unroll
        for (int j = 0; j < QW; ++j) {
            const float4 a = a4[wid * QW + j][g];
            lgq[j] = fmaf(fmaxf(a.x + Bv.x, 0.f), w.x, lgq[j]);
            lgq[j] = fmaf(fmaxf(a.y + Bv.y, 0.f), w.y, lgq[j]);
            lgq[j] = fmaf(fmaxf(a.z + Bv.z, 0.f), w.z, lgq[j]);
            lgq[j] = fmaf(fmaxf(a.w + Bv.w, 0.f), w.w, lgq[j]);
        }
    }

    // ---- mask + direct exp2; stash e into wave-private LDS rows ----
    float ds[QW];
    #pragma unroll
    for (int j = 0; j < QW; ++j) {
        const float4 qp = qp4[wid * QW + j];
        const float dx = qp.x - p.x, dy = qp.y - p.y, dz = qp.z - p.z;
        const float d2 = fmaf(dz, dz, fmaf(dy, dy, dx * dx));
        const bool valid = (p.w == qp.w) & (d2 <= 1.0f);
        const float e = valid ? fast_exp2(lgq[j]) : 0.0f;
        e_lds[wid * QW + j][lane] = e;
        ds[j] = e;
    }
    // denom: 8 interleaved shfl-reduce chains, one atomic per query
    #pragma unroll
    for (int msk = 32; msk; msk >>= 1) {
        #pragma unroll
        for (int j = 0; j < QW; ++j) ds[j] += __shfl_xor(ds[j], msk, 64);
    }
    if (lane == 0) {
        #pragma unroll
        for (int j = 0; j < QW; ++j) atomicAdd(&den[q0 + wid * QW + j], ds[j]);
    }

    // ---- PV: lane = hidden dim; e via b128 broadcast of own wave's rows ----
    const float* Vc = V + ((size_t)c << 12) + lane;
    float pacc[QW];
    #pragma unroll
    for (int j = 0; j < QW; ++j) pacc[j] = 0.0f;
    for (int oo = 0; oo < LDIM; oo += 4) {
        const float v0 = Vc[(oo + 0) << 6];
        const float v1 = Vc[(oo + 1) << 6];
        const float v2 = Vc[(oo + 2) << 6];
        const float v3 = Vc[(oo + 3) << 6];
        #pragma unroll
        for (int j = 0; j < QW; ++j) {
            const float4 e = *(const float4*)&e_lds[wid * QW + j][oo]; // broadcast
            pacc[j] = fmaf(e.x, v0, pacc[j]);
            pacc[j] = fmaf(e.y, v1, pacc[j]);
            pacc[j] = fmaf(e.z, v2, pacc[j]);
            pacc[j] = fmaf(e.w, v3, pacc[j]);
        }
    }
    #pragma unroll
    for (int j = 0; j < QW; ++j)
        atomicAdd(&acc[(size_t)(q0 + wid * QW + j) * LDIM + lane], pacc[j]);
}

// K3: normalize.
__global__ __launch_bounds__(256) void gano_norm(
    const float* __restrict__ acc, const float* __restrict__ den,
    float* __restrict__ out, int n)
{
    const int gid = blockIdx.x * blockDim.x + threadIdx.x;
    if (gid >= n) return;
    out[gid] = acc[gid] / fmaxf(den[gid >> 6], 1e-30f);
}

extern "C" void kernel_launch(void* const* d_in, const int* in_sizes, int n_in,
                              void* d_out, int out_size, void* d_ws, size_t ws_size,
                              hipStream_t stream) {
    const float* h_obs     = (const float*)d_in[0];
    const float* pos_obs   = (const float*)d_in[1];
    const float* pos_query = (const float*)d_in[2];
    const float* W1        = (const float*)d_in[3];
    const float* b1        = (const float*)d_in[4];
    const float* W2        = (const float*)d_in[5];
    // d_in[6] = b2: constant shift, cancels in softmax -> unused
    const float* Wv        = (const float*)d_in[7];
    const float* bv        = (const float*)d_in[8];
    const int* obs_mask    = (const int*)d_in[9];
    const int* obs_batch   = (const int*)d_in[10];
    const int* query_batch = (const int*)d_in[11];

    const int No     = in_sizes[1] / 3;
    const int Nq     = in_sizes[2] / 3;
    const int NoA    = (No + 63) & ~63;
    const int nC     = NoA / 64;
    const int nTiles = (Nq + QT2 - 1) / QT2;

    // ws layout (~1.6 MB)
    float4* Bi  = (float4*)d_ws;                   // NoA*16 float4
    float4* P4  = Bi + (size_t)NoA * 16;           // NoA float4
    float*  V   = (float*)(P4 + NoA);              // NoA*64 f
    float*  A   = V + (size_t)NoA * LDIM;          // Nq*64 f
    float*  w2s = A + (size_t)Nq * LDIM;           // 64 f
    float*  acc = w2s + LDIM;                      // Nq*64 f   (zeroed)
    float*  den = acc + (size_t)Nq * LDIM;         // Nq f      (zeroed, contiguous w/ acc)

    gano_pre<<<(NoA * LDIM + 255) / 256, 256, 0, stream>>>(
        h_obs, pos_obs, pos_query, W1, b1, W2, Wv, bv, obs_mask, obs_batch,
        Bi, P4, V, A, w2s, acc, No, NoA, Nq);

    dim3 g2(nC, nTiles);
    gano_accum<<<g2, 256, 0, stream>>>(Bi, P4, V, A, w2s, pos_query,
                                       obs_batch, query_batch, acc, den, No, Nq);

    gano_norm<<<(Nq * LDIM + 255) / 256, 256, 0, stream>>>(acc, den, (float*)d_out, Nq * LDIM);
}